// Round 1
// 68.098 us; speedup vs baseline: 1.0478x; 1.0478x over previous
//
#include <hip/hip_runtime.h>
#include <math.h>

#define THREADS 256
#define APT 4            // adv points per thread (register tile)
#define TILE 64          // ori points staged per LDS tile
#define RTHREADS 1024    // final-max block

// K1: each thread holds APT adv points in registers (pre-scaled a' = -2*a_scaled,
// intensity channel w scaled 0.5 => a'.w = -w). Each LDS-staged ori point is a
// wave-uniform broadcast read serving 64 lanes x APT pairs.
// Pair cost: 4 fma (chain seeded with b2) + 1 min = 5 VALU ops.
// Cross-chunk combine is fused here: per-adv-point atomicMin on int-viewed
// floats (all values clamped >= 0, so int ordering == float ordering).
// mins[] is pre-set to 0x7F7F7F7F (3.4e38, int-positive "infinity").
__global__ __launch_bounds__(THREADS) void hd_min_atomic(
    const float* __restrict__ adv, const float* __restrict__ ori,
    int* __restrict__ mins,
    int N, int M, int chunks)
{
    __shared__ float4 sb[TILE];
    __shared__ __align__(16) float sb2[TILE];

    const int tid = threadIdx.x;
    const int base_i = blockIdx.x * (THREADS * APT) + tid;

    float4 a[APT];
    #pragma unroll
    for (int k = 0; k < APT; ++k) {
        int i = base_i + k * THREADS;
        float4 v = make_float4(0.f, 0.f, 0.f, 0.f);
        if (i < N) v = ((const float4*)adv)[i];
        // a_scaled = (x,y,z,0.5w); store a' = -2*a_scaled -> (-2x,-2y,-2z,-w)
        a[k].x = -2.0f * v.x;
        a[k].y = -2.0f * v.y;
        a[k].z = -2.0f * v.z;
        a[k].w = -v.w;
    }

    float m[APT];
    #pragma unroll
    for (int k = 0; k < APT; ++k) m[k] = INFINITY;

    for (int base = blockIdx.y * TILE; base < M; base += chunks * TILE) {
        for (int k = tid; k < TILE; k += THREADS) {
            int j = base + k;
            float4 b = make_float4(0.f, 0.f, 0.f, 0.f);
            float b2 = INFINITY;            // pad entries can never win the min
            if (j < M) {
                b = ((const float4*)ori)[j];
                b.w *= 0.5f;
                b2 = b.x*b.x + b.y*b.y + b.z*b.z + b.w*b.w;
            }
            sb[k]  = b;
            sb2[k] = b2;
        }
        __syncthreads();

        #pragma unroll 4
        for (int j = 0; j < TILE; j += 4) {
            // 5 ds_read_b128 (wave-uniform broadcast) serve 4*64*APT pairs
            float4 p0 = sb[j+0], p1 = sb[j+1], p2 = sb[j+2], p3 = sb[j+3];
            float4 q  = ((const float4*)sb2)[j >> 2];
            #pragma unroll
            for (int k = 0; k < APT; ++k) {
                float ax = a[k].x, ay = a[k].y, az = a[k].z, aw = a[k].w;
                float d0 = fmaf(ax, p0.x, fmaf(ay, p0.y, fmaf(az, p0.z, fmaf(aw, p0.w, q.x))));
                float d1 = fmaf(ax, p1.x, fmaf(ay, p1.y, fmaf(az, p1.z, fmaf(aw, p1.w, q.y))));
                float d2 = fmaf(ax, p2.x, fmaf(ay, p2.y, fmaf(az, p2.z, fmaf(aw, p2.w, q.z))));
                float d3 = fmaf(ax, p3.x, fmaf(ay, p3.y, fmaf(az, p3.z, fmaf(aw, p3.w, q.w))));
                // balanced tree; outer pair is min3-fusible
                m[k] = fminf(m[k], fminf(fminf(d0, d1), fminf(d2, d3)));
            }
        }
        __syncthreads();
    }

    #pragma unroll
    for (int k = 0; k < APT; ++k) {
        int i = base_i + k * THREADS;
        if (i < N) {
            // a2 = |a_scaled|^2 = 0.25 * |a'|^2
            float aa = a[k].x*a[k].x + a[k].y*a[k].y + a[k].z*a[k].z + a[k].w*a[k].w;
            float d  = fmaxf(fmaf(0.25f, aa, m[k]), 0.0f);   // >= 0
            atomicMin(&mins[i], __float_as_int(d));          // int order == float order
        }
    }
}

// K2: single-block final max over N non-negative floats (32 KB).
// Plain store to out (exactly one writer) overwrites harness poison.
__global__ __launch_bounds__(RTHREADS) void hd_final_max(
    const int* __restrict__ mins, float* __restrict__ out, int N)
{
    float m = 0.0f;
    for (int i = threadIdx.x; i < N; i += RTHREADS)
        m = fmaxf(m, __int_as_float(mins[i]));
    // wave (64-lane) max reduce
    for (int off = 32; off >= 1; off >>= 1)
        m = fmaxf(m, __shfl_down(m, off, 64));
    __shared__ float smax[RTHREADS / 64];
    int lane = threadIdx.x & 63, wave = threadIdx.x >> 6;
    if (lane == 0) smax[wave] = m;
    __syncthreads();
    if (threadIdx.x == 0) {
        float bm = smax[0];
        #pragma unroll
        for (int w = 1; w < RTHREADS / 64; ++w) bm = fmaxf(bm, smax[w]);
        out[0] = bm;   // LOSS_WEIGHT == 1.0
    }
}

extern "C" void kernel_launch(void* const* d_in, const int* in_sizes, int n_in,
                              void* d_out, int out_size, void* d_ws, size_t ws_size,
                              hipStream_t stream) {
    const float* adv = (const float*)d_in[0];
    const float* ori = (const float*)d_in[1];
    float* out = (float*)d_out;
    int*   mins = (int*)d_ws;

    int N = in_sizes[0] / 4;
    int M = in_sizes[1] / 4;

    int gx    = (N + THREADS * APT - 1) / (THREADS * APT);   // 8 for N=8192
    int N_pad = gx * THREADS * APT;

    // ori chunks: target ~512 blocks total (2/CU); each block covers
    // M/(chunks*TILE) tiles via the strided loop.
    int maxtiles = (M + TILE - 1) / TILE;
    int chunks = 512 / gx;
    if (chunks < 1) chunks = 1;
    if (chunks > maxtiles) chunks = maxtiles;

    // per-iteration init of the min array: 0x7F7F7F7F = 3.4e38 (int-positive
    // "infinity"), so signed-int atomicMin on non-negative floats is correct.
    hipMemsetAsync(mins, 0x7F, (size_t)N_pad * sizeof(int), stream);

    hd_min_atomic<<<dim3(gx, chunks), THREADS, 0, stream>>>(
        adv, ori, mins, N, M, chunks);
    hd_final_max<<<1, RTHREADS, 0, stream>>>(mins, out, N);
}